// Round 1
// baseline (482.920 us; speedup 1.0000x reference)
//
#include <hip/hip_runtime.h>
#include <hip/hip_bf16.h>
#include <stdint.h>

#define T_TOK 2048
#define HD    1024
#define ID    4096
#define NE    8
#define NN2   8192   // 2*ID
#define CHUNK 256    // T_TOK / NE

typedef short          bf16x8 __attribute__((ext_vector_type(8)));
typedef float          f32x4  __attribute__((ext_vector_type(4)));
typedef unsigned short u16;

__device__ __forceinline__ u16 f2bf(float f) {
    return __builtin_bit_cast(u16, __float2bfloat16(f));
}

// ---------------------------------------------------------------- router ----
// One block per token: logits (fp32, exact), argmax -> sigmoid score,
// write scores.T to d_out tail, emit x (bf16) and x*s (bf16) into ws.
__global__ __launch_bounds__(256) void k_router(
    const float* __restrict__ x, const float* __restrict__ rw,
    float* __restrict__ scoresT, u16* __restrict__ xbf, u16* __restrict__ xsbf)
{
    const int t   = blockIdx.x;
    const int tid = threadIdx.x;
    __shared__ float wred[NE][4];
    __shared__ float ssc;

    float4 xv = reinterpret_cast<const float4*>(x + (size_t)t * HD)[tid];
    float p[NE];
#pragma unroll
    for (int e = 0; e < NE; ++e) p[e] = 0.f;
    const float* wrow = rw + (size_t)tid * 4 * NE;
    float xj[4] = {xv.x, xv.y, xv.z, xv.w};
#pragma unroll
    for (int j = 0; j < 4; ++j)
#pragma unroll
        for (int e = 0; e < NE; ++e) p[e] += xj[j] * wrow[j * NE + e];

#pragma unroll
    for (int e = 0; e < NE; ++e) {
        float v = p[e];
#pragma unroll
        for (int o = 32; o > 0; o >>= 1) v += __shfl_down(v, o, 64);
        if ((tid & 63) == 0) wred[e][tid >> 6] = v;
    }
    __syncthreads();
    if (tid == 0) {
        float mx = -3.4e38f; int am = 0;
        float lg[NE];
#pragma unroll
        for (int e = 0; e < NE; ++e) {
            lg[e] = wred[e][0] + wred[e][1] + wred[e][2] + wred[e][3];
            if (lg[e] > mx) { mx = lg[e]; am = e; }
        }
        float sc = 1.f / (1.f + __expf(-mx));
        ssc = sc;
#pragma unroll
        for (int e = 0; e < NE; ++e)
            scoresT[(size_t)e * T_TOK + t] = (e == am) ? sc : 0.f;
    }
    __syncthreads();
    const float sc = ssc;
    ushort4 a, b;
    a.x = f2bf(xj[0]); a.y = f2bf(xj[1]); a.z = f2bf(xj[2]); a.w = f2bf(xj[3]);
    b.x = f2bf(xj[0] * sc); b.y = f2bf(xj[1] * sc); b.z = f2bf(xj[2] * sc); b.w = f2bf(xj[3] * sc);
    reinterpret_cast<ushort4*>(xbf  + (size_t)t * HD)[tid] = a;
    reinterpret_cast<ushort4*>(xsbf + (size_t)t * HD)[tid] = b;
}

// ------------------------------------------------------------------- G1 -----
// H2[t][0:4096]   = silu(x  @ sgw) * (x  @ suw)          (shared expert)
// H2[t][4096:8192]= silu(xs @ GU[g][:, :I]) * (xs @ GU[g][:, I:])  g = t/256
// 128x128 tile, BK=32, 4 waves (2x2), wave tile 64x64, two acc sets.
__global__ __launch_bounds__(256) void k_gemm1(
    const u16* __restrict__ xbf, const u16* __restrict__ xsbf,
    const float* __restrict__ sgw, const float* __restrict__ suw,
    const float* __restrict__ gup, u16* __restrict__ h2)
{
    constexpr int BM = 128, BK = 32;
    const int mt = blockIdx.x, nt = blockIdx.y;
    const int m0 = mt * BM, n0 = nt * 128;

    const u16* A; const float* Bg; const float* Bu; int ldb;
    if (n0 < ID) { A = xbf; Bg = sgw + n0; Bu = suw + n0; ldb = ID; }
    else {
        A = xsbf;
        const int g = m0 / CHUNK;
        Bg = gup + (size_t)g * HD * NN2 + (n0 - ID);
        Bu = Bg + ID;
        ldb = NN2;
    }

    __shared__ u16 As [BM * BK];
    __shared__ u16 Bgs[128 * BK];
    __shared__ u16 Bus[128 * BK];

    const int tid = threadIdx.x;
    const int lane = tid & 63, wid = tid >> 6;
    const int wr = wid >> 1, wc = wid & 1;

    f32x4 accg[4][4], accu[4][4];
#pragma unroll
    for (int i = 0; i < 4; ++i)
#pragma unroll
        for (int j = 0; j < 4; ++j)
#pragma unroll
            for (int r = 0; r < 4; ++r) { accg[i][j][r] = 0.f; accu[i][j][r] = 0.f; }

    // staging maps
    const int arow = tid >> 1, akh = tid & 1;            // A: row, k-half(16)
    const int bcol = tid & 127, bkh = tid >> 7;          // B: col, k-half(16)
    const int asw = (arow >> 1) & 3;
    const int bsw = (bcol >> 1) & 3;
    const u16* aptr = A + (size_t)(m0 + arow) * HD + akh * 16;

    const int lrow = lane & 15, kg = lane >> 4;

    for (int ks = 0; ks < HD / BK; ++ks) {
        const int k0 = ks * BK;
        // global -> regs
        bf16x8 a0 = *reinterpret_cast<const bf16x8*>(aptr + k0);
        bf16x8 a1 = *reinterpret_cast<const bf16x8*>(aptr + k0 + 8);
        const float* bgp = Bg + (size_t)(k0 + bkh * 16) * ldb + bcol;
        const float* bup = Bu + (size_t)(k0 + bkh * 16) * ldb + bcol;
        float gv[16], uv[16];
#pragma unroll
        for (int j = 0; j < 16; ++j) { gv[j] = bgp[(size_t)j * ldb]; uv[j] = bup[(size_t)j * ldb]; }
        bf16x8 wg0, wg1, wu0, wu1;
#pragma unroll
        for (int j = 0; j < 8; ++j) {
            wg0[j] = (short)f2bf(gv[j]); wg1[j] = (short)f2bf(gv[8 + j]);
            wu0[j] = (short)f2bf(uv[j]); wu1[j] = (short)f2bf(uv[8 + j]);
        }
        __syncthreads();   // prior iteration's LDS reads done
        *reinterpret_cast<bf16x8*>(reinterpret_cast<char*>(As)  + arow * 64 + (((akh * 2 + 0) ^ asw) * 16)) = a0;
        *reinterpret_cast<bf16x8*>(reinterpret_cast<char*>(As)  + arow * 64 + (((akh * 2 + 1) ^ asw) * 16)) = a1;
        *reinterpret_cast<bf16x8*>(reinterpret_cast<char*>(Bgs) + bcol * 64 + (((bkh * 2 + 0) ^ bsw) * 16)) = wg0;
        *reinterpret_cast<bf16x8*>(reinterpret_cast<char*>(Bgs) + bcol * 64 + (((bkh * 2 + 1) ^ bsw) * 16)) = wg1;
        *reinterpret_cast<bf16x8*>(reinterpret_cast<char*>(Bus) + bcol * 64 + (((bkh * 2 + 0) ^ bsw) * 16)) = wu0;
        *reinterpret_cast<bf16x8*>(reinterpret_cast<char*>(Bus) + bcol * 64 + (((bkh * 2 + 1) ^ bsw) * 16)) = wu1;
        __syncthreads();
        // LDS -> frags -> MFMA
        bf16x8 af[4], bgf[4], buf2[4];
#pragma unroll
        for (int mf = 0; mf < 4; ++mf) {
            const int row = wr * 64 + mf * 16 + lrow;
            af[mf] = *reinterpret_cast<const bf16x8*>(
                reinterpret_cast<const char*>(As) + row * 64 + ((kg ^ ((row >> 1) & 3)) * 16));
        }
#pragma unroll
        for (int nf = 0; nf < 4; ++nf) {
            const int col = wc * 64 + nf * 16 + lrow;
            const int so  = col * 64 + ((kg ^ ((col >> 1) & 3)) * 16);
            bgf[nf]  = *reinterpret_cast<const bf16x8*>(reinterpret_cast<const char*>(Bgs) + so);
            buf2[nf] = *reinterpret_cast<const bf16x8*>(reinterpret_cast<const char*>(Bus) + so);
        }
#pragma unroll
        for (int mf = 0; mf < 4; ++mf)
#pragma unroll
            for (int nf = 0; nf < 4; ++nf) {
                accg[mf][nf] = __builtin_amdgcn_mfma_f32_16x16x32_bf16(af[mf], bgf[nf],  accg[mf][nf], 0, 0, 0);
                accu[mf][nf] = __builtin_amdgcn_mfma_f32_16x16x32_bf16(af[mf], buf2[nf], accu[mf][nf], 0, 0, 0);
            }
    }
    // SwiGLU epilogue -> bf16 H2
#pragma unroll
    for (int mf = 0; mf < 4; ++mf)
#pragma unroll
        for (int nf = 0; nf < 4; ++nf) {
            const int col = n0 + wc * 64 + nf * 16 + lrow;
#pragma unroll
            for (int r = 0; r < 4; ++r) {
                const int row = m0 + wr * 64 + mf * 16 + (lane >> 4) * 4 + r;
                const float g = accg[mf][nf][r];
                const float u = accu[mf][nf][r];
                const float h = (g / (1.f + __expf(-g))) * u;
                h2[(size_t)row * NN2 + col] = f2bf(h);
            }
        }
}

// ------------------------------------------------------------------- G2 -----
// out = H2[:, :4096] @ shared_down + H2[:, 4096:] @ down[g]   (concat-K GEMM)
// 128x64 tile, BK=32, 4 waves (2x2), wave tile 64x32.
__global__ __launch_bounds__(256) void k_gemm2(
    const u16* __restrict__ h2, const float* __restrict__ sdw,
    const float* __restrict__ dwn, float* __restrict__ out)
{
    constexpr int BM = 128, BK = 32;
    const int mt = blockIdx.x, nt = blockIdx.y;
    const int m0 = mt * BM, n0 = nt * 64;
    const int g  = m0 / CHUNK;

    __shared__ u16 As[BM * BK];
    __shared__ u16 Bs[64 * BK];

    const int tid = threadIdx.x;
    const int lane = tid & 63, wid = tid >> 6;
    const int wr = wid >> 1, wc = wid & 1;

    f32x4 acc[4][2];
#pragma unroll
    for (int i = 0; i < 4; ++i)
#pragma unroll
        for (int j = 0; j < 2; ++j)
#pragma unroll
            for (int r = 0; r < 4; ++r) acc[i][j][r] = 0.f;

    const int arow = tid >> 1, akh = tid & 1;
    const int bcol = tid & 63, bkq = tid >> 6;   // 8 k's each
    const int asw = (arow >> 1) & 3;
    const int bsw = (bcol >> 1) & 3;
    const u16* aptr = h2 + (size_t)(m0 + arow) * NN2 + akh * 16;

    const int lrow = lane & 15, kg = lane >> 4;

    for (int ks = 0; ks < NN2 / BK; ++ks) {
        const int k0 = ks * BK;
        bf16x8 a0 = *reinterpret_cast<const bf16x8*>(aptr + k0);
        bf16x8 a1 = *reinterpret_cast<const bf16x8*>(aptr + k0 + 8);
        const float* bbase = (k0 < ID) ? (sdw + (size_t)k0 * HD)
                                       : (dwn + (size_t)g * ID * HD + (size_t)(k0 - ID) * HD);
        float bv[8];
#pragma unroll
        for (int j = 0; j < 8; ++j) bv[j] = bbase[(size_t)(bkq * 8 + j) * HD + n0 + bcol];
        bf16x8 wB;
#pragma unroll
        for (int j = 0; j < 8; ++j) wB[j] = (short)f2bf(bv[j]);
        __syncthreads();
        *reinterpret_cast<bf16x8*>(reinterpret_cast<char*>(As) + arow * 64 + (((akh * 2 + 0) ^ asw) * 16)) = a0;
        *reinterpret_cast<bf16x8*>(reinterpret_cast<char*>(As) + arow * 64 + (((akh * 2 + 1) ^ asw) * 16)) = a1;
        *reinterpret_cast<bf16x8*>(reinterpret_cast<char*>(Bs) + bcol * 64 + ((bkq ^ bsw) * 16)) = wB;
        __syncthreads();
        bf16x8 af[4], bf2[2];
#pragma unroll
        for (int mf = 0; mf < 4; ++mf) {
            const int row = wr * 64 + mf * 16 + lrow;
            af[mf] = *reinterpret_cast<const bf16x8*>(
                reinterpret_cast<const char*>(As) + row * 64 + ((kg ^ ((row >> 1) & 3)) * 16));
        }
#pragma unroll
        for (int nf = 0; nf < 2; ++nf) {
            const int col = wc * 32 + nf * 16 + lrow;
            bf2[nf] = *reinterpret_cast<const bf16x8*>(
                reinterpret_cast<const char*>(Bs) + col * 64 + ((kg ^ ((col >> 1) & 3)) * 16));
        }
#pragma unroll
        for (int mf = 0; mf < 4; ++mf)
#pragma unroll
            for (int nf = 0; nf < 2; ++nf)
                acc[mf][nf] = __builtin_amdgcn_mfma_f32_16x16x32_bf16(af[mf], bf2[nf], acc[mf][nf], 0, 0, 0);
    }
#pragma unroll
    for (int mf = 0; mf < 4; ++mf)
#pragma unroll
        for (int nf = 0; nf < 2; ++nf) {
            const int col = n0 + wc * 32 + nf * 16 + lrow;
#pragma unroll
            for (int r = 0; r < 4; ++r) {
                const int row = m0 + wr * 64 + mf * 16 + (lane >> 4) * 4 + r;
                out[(size_t)row * HD + col] = acc[mf][nf][r];
            }
        }
}

// --------------------------------------------------------------- launch -----
extern "C" void kernel_launch(void* const* d_in, const int* in_sizes, int n_in,
                              void* d_out, int out_size, void* d_ws, size_t ws_size,
                              hipStream_t stream) {
    const float* x   = (const float*)d_in[0];
    const float* rw  = (const float*)d_in[1];
    const float* gup = (const float*)d_in[2];
    const float* dwn = (const float*)d_in[3];
    const float* sgw = (const float*)d_in[4];
    const float* suw = (const float*)d_in[5];
    const float* sdw = (const float*)d_in[6];

    float* out     = (float*)d_out;
    float* scoresT = out + (size_t)T_TOK * HD;   // (8, 2048) after final

    char* ws   = (char*)d_ws;
    u16* xbf   = (u16*)ws;                                    // 4 MB
    u16* xsbf  = (u16*)(ws + (size_t)T_TOK * HD * 2);         // 4 MB
    u16* h2    = (u16*)(ws + (size_t)2 * T_TOK * HD * 2);     // 32 MB

    k_router<<<T_TOK, 256, 0, stream>>>(x, rw, scoresT, xbf, xsbf);
    dim3 grid1(T_TOK / 128, NN2 / 128);
    k_gemm1<<<grid1, 256, 0, stream>>>(xbf, xsbf, sgw, suw, gup, h2);
    dim3 grid2(T_TOK / 128, HD / 64);
    k_gemm2<<<grid2, 256, 0, stream>>>(h2, sdw, dwn, out);
}

// Round 2
// 307.057 us; speedup vs baseline: 1.5727x; 1.5727x over previous
//
#include <hip/hip_runtime.h>
#include <hip/hip_bf16.h>
#include <stdint.h>

#define T_TOK 2048
#define HD    1024
#define ID    4096
#define NE    8
#define NN2   8192   // 2*ID
#define CHUNK 256    // T_TOK / NE

typedef short          bf16x8 __attribute__((ext_vector_type(8)));
typedef float          f32x4  __attribute__((ext_vector_type(4)));
typedef unsigned short u16;

__device__ __forceinline__ u16 f2bf(float f) {
    return __builtin_bit_cast(u16, __float2bfloat16(f));
}

// ---------------------------------------------------------------- router ----
__global__ __launch_bounds__(256) void k_router(
    const float* __restrict__ x, const float* __restrict__ rw,
    float* __restrict__ scoresT, u16* __restrict__ xbf, u16* __restrict__ xsbf)
{
    const int t   = blockIdx.x;
    const int tid = threadIdx.x;
    __shared__ float wred[NE][4];
    __shared__ float ssc;

    float4 xv = reinterpret_cast<const float4*>(x + (size_t)t * HD)[tid];
    float p[NE];
#pragma unroll
    for (int e = 0; e < NE; ++e) p[e] = 0.f;
    const float* wrow = rw + (size_t)tid * 4 * NE;
    float xj[4] = {xv.x, xv.y, xv.z, xv.w};
#pragma unroll
    for (int j = 0; j < 4; ++j)
#pragma unroll
        for (int e = 0; e < NE; ++e) p[e] += xj[j] * wrow[j * NE + e];

#pragma unroll
    for (int e = 0; e < NE; ++e) {
        float v = p[e];
#pragma unroll
        for (int o = 32; o > 0; o >>= 1) v += __shfl_down(v, o, 64);
        if ((tid & 63) == 0) wred[e][tid >> 6] = v;
    }
    __syncthreads();
    if (tid == 0) {
        float mx = -3.4e38f; int am = 0;
        float lg[NE];
#pragma unroll
        for (int e = 0; e < NE; ++e) {
            lg[e] = wred[e][0] + wred[e][1] + wred[e][2] + wred[e][3];
            if (lg[e] > mx) { mx = lg[e]; am = e; }
        }
        float sc = 1.f / (1.f + __expf(-mx));
        ssc = sc;
#pragma unroll
        for (int e = 0; e < NE; ++e)
            scoresT[(size_t)e * T_TOK + t] = (e == am) ? sc : 0.f;
    }
    __syncthreads();
    const float sc = ssc;
    ushort4 a, b;
    a.x = f2bf(xj[0]); a.y = f2bf(xj[1]); a.z = f2bf(xj[2]); a.w = f2bf(xj[3]);
    b.x = f2bf(xj[0] * sc); b.y = f2bf(xj[1] * sc); b.z = f2bf(xj[2] * sc); b.w = f2bf(xj[3] * sc);
    reinterpret_cast<ushort4*>(xbf  + (size_t)t * HD)[tid] = a;
    reinterpret_cast<ushort4*>(xsbf + (size_t)t * HD)[tid] = b;
}

// ------------------------------------------------------------------- G1 -----
// BM=256 (= CHUNK, one expert per M-tile), BN=128, BK=32, 8 waves (4x2),
// wave tile 64x64, double-buffered LDS, depth-1 prefetch, 1 barrier/step.
__global__ __launch_bounds__(512, 1) void k_gemm1(
    const u16* __restrict__ xbf, const u16* __restrict__ xsbf,
    const float* __restrict__ sgw, const float* __restrict__ suw,
    const float* __restrict__ gup, u16* __restrict__ h2)
{
    constexpr int BM = 256, BN = 128, BK = 32, NS = HD / BK;
    const int mt = blockIdx.x, nt = blockIdx.y;
    const int m0 = mt * BM, n0 = nt * BN;

    const u16* A; const float* Bg; const float* Bu; int ldb;
    if (n0 < ID) { A = xbf; Bg = sgw + n0; Bu = suw + n0; ldb = ID; }
    else {
        A = xsbf;
        Bg = gup + (size_t)mt * HD * NN2 + (n0 - ID);
        Bu = Bg + ID;
        ldb = NN2;
    }

    __shared__ u16 As [2][BM * BK];
    __shared__ u16 Bgs[2][BN * BK];
    __shared__ u16 Bus[2][BN * BK];

    const int tid = threadIdx.x;
    const int lane = tid & 63, wid = tid >> 6;
    const int wr = wid >> 1, wc = wid & 1;          // 4 x 2 wave grid
    const int lrow = lane & 15, kg = lane >> 4;

    f32x4 accg[4][4], accu[4][4];
#pragma unroll
    for (int i = 0; i < 4; ++i)
#pragma unroll
        for (int j = 0; j < 4; ++j)
#pragma unroll
            for (int r = 0; r < 4; ++r) { accg[i][j][r] = 0.f; accu[i][j][r] = 0.f; }

    // staging maps
    const int arow = tid >> 1, akh = tid & 1;        // A: 256 rows, k-half of 16
    const int asw  = (arow >> 1) & 3;
    const int bcol = tid & 127, bkh = tid >> 7;      // B: 128 cols, k-group of 8
    const int bsw  = (bcol >> 1) & 3;
    const u16* aptr = A + (size_t)(m0 + arow) * HD + akh * 16;

    bf16x8 ra0, ra1;
    float  rg[8], ru[8];

    auto LOAD = [&](int ks) {
        const int k0 = ks * BK;
        ra0 = *reinterpret_cast<const bf16x8*>(aptr + k0);
        ra1 = *reinterpret_cast<const bf16x8*>(aptr + k0 + 8);
        const float* bgp = Bg + (size_t)(k0 + bkh * 8) * ldb + bcol;
        const float* bup = Bu + (size_t)(k0 + bkh * 8) * ldb + bcol;
#pragma unroll
        for (int j = 0; j < 8; ++j) { rg[j] = bgp[(size_t)j * ldb]; ru[j] = bup[(size_t)j * ldb]; }
    };
    auto STORE = [&](int b) {
        char* as = (char*)As[b]; char* gs = (char*)Bgs[b]; char* us = (char*)Bus[b];
        *reinterpret_cast<bf16x8*>(as + arow * 64 + (((akh * 2 + 0) ^ asw) * 16)) = ra0;
        *reinterpret_cast<bf16x8*>(as + arow * 64 + (((akh * 2 + 1) ^ asw) * 16)) = ra1;
        bf16x8 wg, wu;
#pragma unroll
        for (int j = 0; j < 8; ++j) { wg[j] = (short)f2bf(rg[j]); wu[j] = (short)f2bf(ru[j]); }
        *reinterpret_cast<bf16x8*>(gs + bcol * 64 + ((bkh ^ bsw) * 16)) = wg;
        *reinterpret_cast<bf16x8*>(us + bcol * 64 + ((bkh ^ bsw) * 16)) = wu;
    };

    LOAD(0);
    STORE(0);
    __syncthreads();
    int cur = 0;

    for (int ks = 0; ks < NS; ++ks) {
        if (ks + 1 < NS) LOAD(ks + 1);                 // issue early: in flight over MFMA
        const char* as = (const char*)As[cur];
        const char* gs = (const char*)Bgs[cur];
        const char* us = (const char*)Bus[cur];
        bf16x8 af[4], bgf[4], buf2[4];
#pragma unroll
        for (int mf = 0; mf < 4; ++mf) {
            const int row = wr * 64 + mf * 16 + lrow;
            af[mf] = *reinterpret_cast<const bf16x8*>(as + row * 64 + ((kg ^ ((row >> 1) & 3)) * 16));
        }
#pragma unroll
        for (int nf = 0; nf < 4; ++nf) {
            const int col = wc * 64 + nf * 16 + lrow;
            const int so  = col * 64 + ((kg ^ ((col >> 1) & 3)) * 16);
            bgf[nf]  = *reinterpret_cast<const bf16x8*>(gs + so);
            buf2[nf] = *reinterpret_cast<const bf16x8*>(us + so);
        }
#pragma unroll
        for (int mf = 0; mf < 4; ++mf)
#pragma unroll
            for (int nf = 0; nf < 4; ++nf) {
                accg[mf][nf] = __builtin_amdgcn_mfma_f32_16x16x32_bf16(af[mf], bgf[nf],  accg[mf][nf], 0, 0, 0);
                accu[mf][nf] = __builtin_amdgcn_mfma_f32_16x16x32_bf16(af[mf], buf2[nf], accu[mf][nf], 0, 0, 0);
            }
        if (ks + 1 < NS) STORE(cur ^ 1);
        __syncthreads();
        cur ^= 1;
    }

    // SwiGLU epilogue -> bf16 H2
#pragma unroll
    for (int mf = 0; mf < 4; ++mf)
#pragma unroll
        for (int nf = 0; nf < 4; ++nf) {
            const int col = n0 + wc * 64 + nf * 16 + lrow;
#pragma unroll
            for (int r = 0; r < 4; ++r) {
                const int row = m0 + wr * 64 + mf * 16 + kg * 4 + r;
                const float g = accg[mf][nf][r];
                const float u = accu[mf][nf][r];
                const float h = (g / (1.f + __expf(-g))) * u;
                h2[(size_t)row * NN2 + col] = f2bf(h);
            }
        }
}

// ------------------------------------------------------------------- G2 -----
// out = H2[:, :4096] @ shared_down + H2[:, 4096:] @ down[g]  (concat-K GEMM)
// BM=128, BN=64, BK=64, 4 waves (2x2), wave tile 64x32, double-buffered,
// depth-1 prefetch, 1 barrier/step.
__global__ __launch_bounds__(256, 1) void k_gemm2(
    const u16* __restrict__ h2, const float* __restrict__ sdw,
    const float* __restrict__ dwn, float* __restrict__ out)
{
    constexpr int BM = 128, BN = 64, BK = 64, NS = NN2 / BK;
    const int mt = blockIdx.x, nt = blockIdx.y;
    const int m0 = mt * BM, n0 = nt * BN;
    const int g  = mt >> 1;                          // m0 / CHUNK

    __shared__ u16 As[2][BM * BK];
    __shared__ u16 Bs[2][BN * BK];

    const int tid = threadIdx.x;
    const int lane = tid & 63, wid = tid >> 6;
    const int wr = wid >> 1, wc = wid & 1;
    const int lrow = lane & 15, kg = lane >> 4;

    f32x4 acc[4][2];
#pragma unroll
    for (int i = 0; i < 4; ++i)
#pragma unroll
        for (int j = 0; j < 2; ++j)
#pragma unroll
            for (int r = 0; r < 4; ++r) acc[i][j][r] = 0.f;

    const int arow = tid >> 1, ahalf = tid & 1;      // A: 128 rows, 32-k halves
    const int bcol = tid & 63,  bkq  = tid >> 6;     // B: 64 cols, 16-k quarters
    const u16* aptr = h2 + (size_t)(m0 + arow) * NN2 + ahalf * 32;

    bf16x8 ra[4];
    float  rb[16];

    auto LOAD = [&](int ks) {
        const int k0 = ks * BK;
#pragma unroll
        for (int c = 0; c < 4; ++c)
            ra[c] = *reinterpret_cast<const bf16x8*>(aptr + k0 + c * 8);
        const float* bbase = (k0 < ID) ? (sdw + (size_t)k0 * HD)
                                       : (dwn + (size_t)g * ID * HD + (size_t)(k0 - ID) * HD);
#pragma unroll
        for (int j = 0; j < 16; ++j)
            rb[j] = bbase[(size_t)(bkq * 16 + j) * HD + n0 + bcol];
    };
    auto STORE = [&](int b) {
        char* as = (char*)As[b]; char* bs = (char*)Bs[b];
#pragma unroll
        for (int c = 0; c < 4; ++c)
            *reinterpret_cast<bf16x8*>(as + arow * 128 + (((ahalf * 4 + c) ^ (arow & 7)) * 16)) = ra[c];
        bf16x8 w0, w1;
#pragma unroll
        for (int j = 0; j < 8; ++j) { w0[j] = (short)f2bf(rb[j]); w1[j] = (short)f2bf(rb[8 + j]); }
        *reinterpret_cast<bf16x8*>(bs + bcol * 128 + (((bkq * 2 + 0) ^ (bcol & 7)) * 16)) = w0;
        *reinterpret_cast<bf16x8*>(bs + bcol * 128 + (((bkq * 2 + 1) ^ (bcol & 7)) * 16)) = w1;
    };

    LOAD(0);
    STORE(0);
    __syncthreads();
    int cur = 0;

    for (int ks = 0; ks < NS; ++ks) {
        if (ks + 1 < NS) LOAD(ks + 1);
        const char* as = (const char*)As[cur];
        const char* bs = (const char*)Bs[cur];
#pragma unroll
        for (int kk = 0; kk < 2; ++kk) {
            bf16x8 af[4], bf2[2];
#pragma unroll
            for (int mf = 0; mf < 4; ++mf) {
                const int row = wr * 64 + mf * 16 + lrow;
                af[mf] = *reinterpret_cast<const bf16x8*>(
                    as + row * 128 + (((kk * 4 + kg) ^ (row & 7)) * 16));
            }
#pragma unroll
            for (int nf = 0; nf < 2; ++nf) {
                const int col = wc * 32 + nf * 16 + lrow;
                bf2[nf] = *reinterpret_cast<const bf16x8*>(
                    bs + col * 128 + (((kk * 4 + kg) ^ (col & 7)) * 16));
            }
#pragma unroll
            for (int mf = 0; mf < 4; ++mf)
#pragma unroll
                for (int nf = 0; nf < 2; ++nf)
                    acc[mf][nf] = __builtin_amdgcn_mfma_f32_16x16x32_bf16(af[mf], bf2[nf], acc[mf][nf], 0, 0, 0);
        }
        if (ks + 1 < NS) STORE(cur ^ 1);
        __syncthreads();
        cur ^= 1;
    }

#pragma unroll
    for (int mf = 0; mf < 4; ++mf)
#pragma unroll
        for (int nf = 0; nf < 2; ++nf) {
            const int col = n0 + wc * 32 + nf * 16 + lrow;
#pragma unroll
            for (int r = 0; r < 4; ++r) {
                const int row = m0 + wr * 64 + mf * 16 + kg * 4 + r;
                out[(size_t)row * HD + col] = acc[mf][nf][r];
            }
        }
}

// --------------------------------------------------------------- launch -----
extern "C" void kernel_launch(void* const* d_in, const int* in_sizes, int n_in,
                              void* d_out, int out_size, void* d_ws, size_t ws_size,
                              hipStream_t stream) {
    const float* x   = (const float*)d_in[0];
    const float* rw  = (const float*)d_in[1];
    const float* gup = (const float*)d_in[2];
    const float* dwn = (const float*)d_in[3];
    const float* sgw = (const float*)d_in[4];
    const float* suw = (const float*)d_in[5];
    const float* sdw = (const float*)d_in[6];

    float* out     = (float*)d_out;
    float* scoresT = out + (size_t)T_TOK * HD;

    char* ws   = (char*)d_ws;
    u16* xbf   = (u16*)ws;                                    // 4 MB
    u16* xsbf  = (u16*)(ws + (size_t)T_TOK * HD * 2);         // 4 MB
    u16* h2    = (u16*)(ws + (size_t)2 * T_TOK * HD * 2);     // 32 MB

    k_router<<<T_TOK, 256, 0, stream>>>(x, rw, scoresT, xbf, xsbf);
    dim3 grid1(T_TOK / 256, NN2 / 128);
    k_gemm1<<<grid1, 512, 0, stream>>>(xbf, xsbf, sgw, suw, gup, h2);
    dim3 grid2(T_TOK / 128, HD / 64);
    k_gemm2<<<grid2, 256, 0, stream>>>(h2, sdw, dwn, out);
}